// Round 1
// baseline (14481.013 us; speedup 1.0000x reference)
//
#include <hip/hip_runtime.h>
#include <hip/hip_bf16.h>

#define DD 128
#define PAD 132   // padded LDS row stride (floats), 16B-aligned, avoids 4-way bank conflict

// ---------------------------------------------------------------------------
// scatter_add: agg[dst[e]] += h[src[e]]  (128 floats per edge, 32 threads/edge)
// ---------------------------------------------------------------------------
__global__ __launch_bounds__(256) void scatter_add_k(
    const float* __restrict__ h, const int* __restrict__ src,
    const int* __restrict__ dst, float* __restrict__ agg, int nEdges)
{
    int gid = blockIdx.x * 256 + threadIdx.x;
    int e = gid >> 5;
    int j = gid & 31;
    if (e < nEdges) {
        int s = src[e];
        int t = dst[e];
        float4 v = ((const float4*)(h + (size_t)s * DD))[j];
        float* p = agg + (size_t)t * DD + j * 4;
        atomicAdd(p + 0, v.x);
        atomicAdd(p + 1, v.y);
        atomicAdd(p + 2, v.z);
        atomicAdd(p + 3, v.w);
    }
}

// ---------------------------------------------------------------------------
// Fused GEMM: out = relu(epilogue((inA [+ inB]) @ W + bias))
//   W is [128][128] row-major (k, n). Tile: 128 rows x 128 cols per block,
//   256 threads, each thread 8 rows x 8 cols. W + input staged in LDS.
//   BN epilogue: y = dot*s + (bias-mean)*s + beta,  s = gamma*rsqrt(var+eps)
//   Safe when out aliases inA or inB (tile fully staged before writes).
// ---------------------------------------------------------------------------
template <bool SUM2, bool BN>
__global__ __launch_bounds__(256) void gemm_fused_k(
    const float* __restrict__ inA, const float* __restrict__ inB,
    const float* __restrict__ W, const float* __restrict__ bias,
    const float* __restrict__ gamma, const float* __restrict__ beta,
    const float* __restrict__ mean, const float* __restrict__ var,
    float* __restrict__ out, int nrows)
{
    extern __shared__ float lds[];
    float* sW  = lds;             // 128*128 floats = 64KB
    float* sIn = lds + DD * DD;   // 128*PAD floats = 66KB

    const int tid  = threadIdx.x;
    const int row0 = blockIdx.x * 128;

    // stage W (coalesced float4)
    {
        const float4* Wv = (const float4*)W;
        float4* sWv = (float4*)sW;
#pragma unroll
        for (int i = 0; i < 16; ++i) sWv[i * 256 + tid] = Wv[i * 256 + tid];
    }
    // stage input tile (128 rows), zero-fill OOB rows
    {
#pragma unroll
        for (int i = 0; i < 16; ++i) {
            int e4 = i * 256 + tid;   // float4 index within tile
            int r  = e4 >> 5;         // 32 float4 per row
            int c4 = e4 & 31;
            int gr = row0 + r;
            float4 v = make_float4(0.f, 0.f, 0.f, 0.f);
            if (gr < nrows) {
                v = ((const float4*)(inA + (size_t)gr * DD))[c4];
                if (SUM2) {
                    float4 u = ((const float4*)(inB + (size_t)gr * DD))[c4];
                    v.x += u.x; v.y += u.y; v.z += u.z; v.w += u.w;
                }
            }
            *(float4*)&sIn[r * PAD + c4 * 4] = v;
        }
    }
    __syncthreads();

    const int cg = tid & 15;   // 16 col groups * 8 cols
    const int rg = tid >> 4;   // 16 row groups; rows rg + r*16 (stride-16 interleave)

    float acc[8][8];
#pragma unroll
    for (int r = 0; r < 8; ++r)
#pragma unroll
        for (int c = 0; c < 8; ++c) acc[r][c] = 0.f;

    for (int k0 = 0; k0 < DD; k0 += 4) {
        float4 a[8];
#pragma unroll
        for (int r = 0; r < 8; ++r)
            a[r] = *(const float4*)&sIn[(rg + r * 16) * PAD + k0];
        float4 b0[4], b1[4];
#pragma unroll
        for (int kk = 0; kk < 4; ++kk) {
            b0[kk] = *(const float4*)&sW[(k0 + kk) * DD + cg * 8];
            b1[kk] = *(const float4*)&sW[(k0 + kk) * DD + cg * 8 + 4];
        }
#pragma unroll
        for (int r = 0; r < 8; ++r) {
            float as[4] = {a[r].x, a[r].y, a[r].z, a[r].w};
#pragma unroll
            for (int kk = 0; kk < 4; ++kk) {
                float s = as[kk];
                acc[r][0] = fmaf(s, b0[kk].x, acc[r][0]);
                acc[r][1] = fmaf(s, b0[kk].y, acc[r][1]);
                acc[r][2] = fmaf(s, b0[kk].z, acc[r][2]);
                acc[r][3] = fmaf(s, b0[kk].w, acc[r][3]);
                acc[r][4] = fmaf(s, b1[kk].x, acc[r][4]);
                acc[r][5] = fmaf(s, b1[kk].y, acc[r][5]);
                acc[r][6] = fmaf(s, b1[kk].z, acc[r][6]);
                acc[r][7] = fmaf(s, b1[kk].w, acc[r][7]);
            }
        }
    }

    // epilogue
    const int cbase = cg * 8;
    float mul[8], add[8];
#pragma unroll
    for (int c = 0; c < 8; ++c) {
        int col = cbase + c;
        if (BN) {
            float s = gamma[col] * rsqrtf(var[col] + 1e-5f);
            mul[c] = s;
            add[c] = (bias[col] - mean[col]) * s + beta[col];
        } else {
            mul[c] = 1.f;
            add[c] = bias[col];
        }
    }
#pragma unroll
    for (int r = 0; r < 8; ++r) {
        int grow = row0 + rg + r * 16;
        if (grow < nrows) {
            float4 o0, o1;
            o0.x = fmaxf(fmaf(acc[r][0], mul[0], add[0]), 0.f);
            o0.y = fmaxf(fmaf(acc[r][1], mul[1], add[1]), 0.f);
            o0.z = fmaxf(fmaf(acc[r][2], mul[2], add[2]), 0.f);
            o0.w = fmaxf(fmaf(acc[r][3], mul[3], add[3]), 0.f);
            o1.x = fmaxf(fmaf(acc[r][4], mul[4], add[4]), 0.f);
            o1.y = fmaxf(fmaf(acc[r][5], mul[5], add[5]), 0.f);
            o1.z = fmaxf(fmaf(acc[r][6], mul[6], add[6]), 0.f);
            o1.w = fmaxf(fmaf(acc[r][7], mul[7], add[7]), 0.f);
            float* op = out + (size_t)grow * DD + cbase;
            *(float4*)(op)     = o0;
            *(float4*)(op + 4) = o1;
        }
    }
}

// ---------------------------------------------------------------------------
// lin2 (128 -> 10) + log_softmax. One wave (64 lanes) per row.
// ---------------------------------------------------------------------------
__global__ __launch_bounds__(256) void lin2_lsm_k(
    const float* __restrict__ in, const float* __restrict__ w /*[128][10]*/,
    const float* __restrict__ b, float* __restrict__ out, int n)
{
    int tid  = threadIdx.x;
    int lane = tid & 63;
    int row  = blockIdx.x * 4 + (tid >> 6);
    if (row >= n) return;

    const float* hr = in + (size_t)row * DD;
    float x0 = hr[lane];
    float x1 = hr[lane + 64];

    float p[10];
#pragma unroll
    for (int c = 0; c < 10; ++c)
        p[c] = fmaf(x0, w[lane * 10 + c], x1 * w[(lane + 64) * 10 + c]);

#pragma unroll
    for (int off = 32; off >= 1; off >>= 1) {
#pragma unroll
        for (int c = 0; c < 10; ++c) p[c] += __shfl_xor(p[c], off, 64);
    }
#pragma unroll
    for (int c = 0; c < 10; ++c) p[c] += b[c];

    float m = p[0];
#pragma unroll
    for (int c = 1; c < 10; ++c) m = fmaxf(m, p[c]);
    float s = 0.f;
#pragma unroll
    for (int c = 0; c < 10; ++c) s += expf(p[c] - m);
    float lse = m + logf(s);

    if (lane < 10) out[(size_t)row * 10 + lane] = p[lane] - lse;
}

// ---------------------------------------------------------------------------

extern "C" void kernel_launch(void* const* d_in, const int* in_sizes, int n_in,
                              void* d_out, int out_size, void* d_ws, size_t ws_size,
                              hipStream_t stream)
{
    const float* x      = (const float*)d_in[0];
    const int*   ei     = (const int*)d_in[1];
    const float* W1     = (const float*)d_in[2];
    const float* b1     = (const float*)d_in[3];
    const float* gamma  = (const float*)d_in[4];
    const float* beta   = (const float*)d_in[5];
    const float* mean   = (const float*)d_in[6];
    const float* var    = (const float*)d_in[7];
    const float* W2     = (const float*)d_in[8];
    const float* b2     = (const float*)d_in[9];
    const float* lin1_w = (const float*)d_in[10];
    const float* lin1_b = (const float*)d_in[11];
    const float* lin2_w = (const float*)d_in[12];
    const float* lin2_b = (const float*)d_in[13];

    const int N = in_sizes[0] / DD;
    const int E = in_sizes[1] / 2;
    const int* srcI = ei;
    const int* dstI = ei + E;

    float* A = (float*)d_ws;                 // h buffer
    float* G = A + (size_t)N * DD;           // agg / z buffer

    const size_t ldsBytes = (size_t)(DD * DD + DD * PAD) * sizeof(float); // 130KB
    // opt-in for >64KB dynamic LDS (no-op if unsupported); errors ignored
    (void)hipFuncSetAttribute((const void*)gemm_fused_k<true, true>,
                              hipFuncAttributeMaxDynamicSharedMemorySize, (int)ldsBytes);
    (void)hipFuncSetAttribute((const void*)gemm_fused_k<false, false>,
                              hipFuncAttributeMaxDynamicSharedMemorySize, (int)ldsBytes);

    const int gemmGrid    = (N + 127) / 128;
    const int scatterGrid = (E * 32 + 255) / 256;

    const float* hcur = x;
    for (int l = 0; l < 5; ++l) {
        hipMemsetAsync(G, 0, (size_t)N * DD * sizeof(float), stream);
        scatter_add_k<<<scatterGrid, 256, 0, stream>>>(hcur, srcI, dstI, G, E);
        // z = relu(BN((h+agg) @ W1 + b1))  -> G (aliases agg input, safe: tile staged)
        gemm_fused_k<true, true><<<gemmGrid, 256, ldsBytes, stream>>>(
            hcur, G, W1 + (size_t)l * DD * DD, b1 + (size_t)l * DD,
            gamma + (size_t)l * DD, beta + (size_t)l * DD,
            mean + (size_t)l * DD, var + (size_t)l * DD, G, N);
        // h = relu(z @ W2 + b2) -> A
        gemm_fused_k<false, false><<<gemmGrid, 256, ldsBytes, stream>>>(
            G, nullptr, W2 + (size_t)l * DD * DD, b2 + (size_t)l * DD,
            nullptr, nullptr, nullptr, nullptr, A, N);
        hcur = A;
    }
    // lin1: h = relu(h @ lin1_w + lin1_b) -> G
    gemm_fused_k<false, false><<<gemmGrid, 256, ldsBytes, stream>>>(
        A, nullptr, lin1_w, lin1_b, nullptr, nullptr, nullptr, nullptr, G, N);
    // lin2 + log_softmax -> out
    lin2_lsm_k<<<(N + 3) / 4, 256, 0, stream>>>(G, lin2_w, lin2_b, (float*)d_out, N);
}

// Round 2
// 1967.054 us; speedup vs baseline: 7.3618x; 7.3618x over previous
//
#include <hip/hip_runtime.h>
#include <hip/hip_bf16.h>

#define DD 128
#define PAD 132   // padded LDS row stride (floats)

// ---------------------------------------------------------------------------
// CSR build: histogram -> exclusive scan -> fill
// ---------------------------------------------------------------------------
__global__ __launch_bounds__(256) void hist_k(
    const int* __restrict__ dst, int* __restrict__ cnt, int nEdges)
{
    int e = blockIdx.x * 256 + threadIdx.x;
    if (e < nEdges) atomicAdd(&cnt[dst[e]], 1);
}

// single block, 1024 threads: exclusive scan of cnt[0..n) -> rowptr, cursor
__global__ __launch_bounds__(1024) void scan_k(
    const int* __restrict__ cnt, int* __restrict__ rowptr,
    int* __restrict__ cursor, int n, int nPerT)
{
    __shared__ int s[1024];
    const int t = threadIdx.x;
    const int beg = t * nPerT;
    const int end = min(beg + nPerT, n);
    int sum = 0;
    for (int i = beg; i < end; ++i) sum += cnt[i];
    s[t] = sum;
    __syncthreads();
    int mySum = sum;
    for (int off = 1; off < 1024; off <<= 1) {
        int v = (t >= off) ? s[t - off] : 0;
        __syncthreads();
        s[t] += v;
        __syncthreads();
    }
    int run = s[t] - mySum;   // exclusive prefix
    for (int i = beg; i < end; ++i) {
        int c = cnt[i];       // read before any aliased write (cursor may alias cnt)
        rowptr[i] = run;
        cursor[i] = run;
        run += c;
    }
    if (t == 1023) rowptr[n] = s[1023];
}

__global__ __launch_bounds__(256) void fill_k(
    const int* __restrict__ src, const int* __restrict__ dst,
    int* __restrict__ cursor, int* __restrict__ csr, int nEdges)
{
    int e = blockIdx.x * 256 + threadIdx.x;
    if (e < nEdges) {
        int d = dst[e];
        int pos = atomicAdd(&cursor[d], 1);
        csr[pos] = src[e];
    }
}

// ---------------------------------------------------------------------------
// gather: agg[i] = sum_{k in [rowptr[i],rowptr[i+1])} h[csr[k]]
//   32 lanes per node (float4 each), 8 nodes per 256-thread block.
// ---------------------------------------------------------------------------
__global__ __launch_bounds__(256) void gather_k(
    const float* __restrict__ h, const int* __restrict__ rowptr,
    const int* __restrict__ csr, float* __restrict__ agg, int n)
{
    int node = blockIdx.x * 8 + (threadIdx.x >> 5);
    int j = threadIdx.x & 31;
    if (node >= n) return;
    int beg = rowptr[node];
    int end = rowptr[node + 1];

    float4 a0 = make_float4(0.f, 0.f, 0.f, 0.f);
    float4 a1 = make_float4(0.f, 0.f, 0.f, 0.f);
    int k = beg;
    for (; k + 1 < end; k += 2) {
        int s0 = csr[k];
        int s1 = csr[k + 1];
        float4 v0 = ((const float4*)(h + (size_t)s0 * DD))[j];
        float4 v1 = ((const float4*)(h + (size_t)s1 * DD))[j];
        a0.x += v0.x; a0.y += v0.y; a0.z += v0.z; a0.w += v0.w;
        a1.x += v1.x; a1.y += v1.y; a1.z += v1.z; a1.w += v1.w;
    }
    if (k < end) {
        int s0 = csr[k];
        float4 v0 = ((const float4*)(h + (size_t)s0 * DD))[j];
        a0.x += v0.x; a0.y += v0.y; a0.z += v0.z; a0.w += v0.w;
    }
    a0.x += a1.x; a0.y += a1.y; a0.z += a1.z; a0.w += a1.w;
    ((float4*)(agg + (size_t)node * DD))[j] = a0;
}

// ---------------------------------------------------------------------------
// Fused GEMM: out = relu(epilogue((inA [+ inB]) @ W + bias))  (unchanged)
// ---------------------------------------------------------------------------
template <bool SUM2, bool BN>
__global__ __launch_bounds__(256) void gemm_fused_k(
    const float* __restrict__ inA, const float* __restrict__ inB,
    const float* __restrict__ W, const float* __restrict__ bias,
    const float* __restrict__ gamma, const float* __restrict__ beta,
    const float* __restrict__ mean, const float* __restrict__ var,
    float* __restrict__ out, int nrows)
{
    extern __shared__ float lds[];
    float* sW  = lds;             // 128*128 floats
    float* sIn = lds + DD * DD;   // 128*PAD floats

    const int tid  = threadIdx.x;
    const int row0 = blockIdx.x * 128;

    {
        const float4* Wv = (const float4*)W;
        float4* sWv = (float4*)sW;
#pragma unroll
        for (int i = 0; i < 16; ++i) sWv[i * 256 + tid] = Wv[i * 256 + tid];
    }
    {
#pragma unroll
        for (int i = 0; i < 16; ++i) {
            int e4 = i * 256 + tid;
            int r  = e4 >> 5;
            int c4 = e4 & 31;
            int gr = row0 + r;
            float4 v = make_float4(0.f, 0.f, 0.f, 0.f);
            if (gr < nrows) {
                v = ((const float4*)(inA + (size_t)gr * DD))[c4];
                if (SUM2) {
                    float4 u = ((const float4*)(inB + (size_t)gr * DD))[c4];
                    v.x += u.x; v.y += u.y; v.z += u.z; v.w += u.w;
                }
            }
            *(float4*)&sIn[r * PAD + c4 * 4] = v;
        }
    }
    __syncthreads();

    const int cg = tid & 15;
    const int rg = tid >> 4;

    float acc[8][8];
#pragma unroll
    for (int r = 0; r < 8; ++r)
#pragma unroll
        for (int c = 0; c < 8; ++c) acc[r][c] = 0.f;

    for (int k0 = 0; k0 < DD; k0 += 4) {
        float4 a[8];
#pragma unroll
        for (int r = 0; r < 8; ++r)
            a[r] = *(const float4*)&sIn[(rg + r * 16) * PAD + k0];
        float4 b0[4], b1[4];
#pragma unroll
        for (int kk = 0; kk < 4; ++kk) {
            b0[kk] = *(const float4*)&sW[(k0 + kk) * DD + cg * 8];
            b1[kk] = *(const float4*)&sW[(k0 + kk) * DD + cg * 8 + 4];
        }
#pragma unroll
        for (int r = 0; r < 8; ++r) {
            float as[4] = {a[r].x, a[r].y, a[r].z, a[r].w};
#pragma unroll
            for (int kk = 0; kk < 4; ++kk) {
                float s = as[kk];
                acc[r][0] = fmaf(s, b0[kk].x, acc[r][0]);
                acc[r][1] = fmaf(s, b0[kk].y, acc[r][1]);
                acc[r][2] = fmaf(s, b0[kk].z, acc[r][2]);
                acc[r][3] = fmaf(s, b0[kk].w, acc[r][3]);
                acc[r][4] = fmaf(s, b1[kk].x, acc[r][4]);
                acc[r][5] = fmaf(s, b1[kk].y, acc[r][5]);
                acc[r][6] = fmaf(s, b1[kk].z, acc[r][6]);
                acc[r][7] = fmaf(s, b1[kk].w, acc[r][7]);
            }
        }
    }

    const int cbase = cg * 8;
    float mul[8], add[8];
#pragma unroll
    for (int c = 0; c < 8; ++c) {
        int col = cbase + c;
        if (BN) {
            float s = gamma[col] * rsqrtf(var[col] + 1e-5f);
            mul[c] = s;
            add[c] = (bias[col] - mean[col]) * s + beta[col];
        } else {
            mul[c] = 1.f;
            add[c] = bias[col];
        }
    }
#pragma unroll
    for (int r = 0; r < 8; ++r) {
        int grow = row0 + rg + r * 16;
        if (grow < nrows) {
            float4 o0, o1;
            o0.x = fmaxf(fmaf(acc[r][0], mul[0], add[0]), 0.f);
            o0.y = fmaxf(fmaf(acc[r][1], mul[1], add[1]), 0.f);
            o0.z = fmaxf(fmaf(acc[r][2], mul[2], add[2]), 0.f);
            o0.w = fmaxf(fmaf(acc[r][3], mul[3], add[3]), 0.f);
            o1.x = fmaxf(fmaf(acc[r][4], mul[4], add[4]), 0.f);
            o1.y = fmaxf(fmaf(acc[r][5], mul[5], add[5]), 0.f);
            o1.z = fmaxf(fmaf(acc[r][6], mul[6], add[6]), 0.f);
            o1.w = fmaxf(fmaf(acc[r][7], mul[7], add[7]), 0.f);
            float* op = out + (size_t)grow * DD + cbase;
            *(float4*)(op)     = o0;
            *(float4*)(op + 4) = o1;
        }
    }
}

// ---------------------------------------------------------------------------
// lin2 (128 -> 10) + log_softmax. One wave per row.
// ---------------------------------------------------------------------------
__global__ __launch_bounds__(256) void lin2_lsm_k(
    const float* __restrict__ in, const float* __restrict__ w,
    const float* __restrict__ b, float* __restrict__ out, int n)
{
    int tid  = threadIdx.x;
    int lane = tid & 63;
    int row  = blockIdx.x * 4 + (tid >> 6);
    if (row >= n) return;

    const float* hr = in + (size_t)row * DD;
    float x0 = hr[lane];
    float x1 = hr[lane + 64];

    float p[10];
#pragma unroll
    for (int c = 0; c < 10; ++c)
        p[c] = fmaf(x0, w[lane * 10 + c], x1 * w[(lane + 64) * 10 + c]);

#pragma unroll
    for (int off = 32; off >= 1; off >>= 1) {
#pragma unroll
        for (int c = 0; c < 10; ++c) p[c] += __shfl_xor(p[c], off, 64);
    }
#pragma unroll
    for (int c = 0; c < 10; ++c) p[c] += b[c];

    float m = p[0];
#pragma unroll
    for (int c = 1; c < 10; ++c) m = fmaxf(m, p[c]);
    float s = 0.f;
#pragma unroll
    for (int c = 0; c < 10; ++c) s += expf(p[c] - m);
    float lse = m + logf(s);

    if (lane < 10) out[(size_t)row * 10 + lane] = p[lane] - lse;
}

// ---------------------------------------------------------------------------

extern "C" void kernel_launch(void* const* d_in, const int* in_sizes, int n_in,
                              void* d_out, int out_size, void* d_ws, size_t ws_size,
                              hipStream_t stream)
{
    const float* x      = (const float*)d_in[0];
    const int*   ei     = (const int*)d_in[1];
    const float* W1     = (const float*)d_in[2];
    const float* b1     = (const float*)d_in[3];
    const float* gamma  = (const float*)d_in[4];
    const float* beta   = (const float*)d_in[5];
    const float* mean   = (const float*)d_in[6];
    const float* var    = (const float*)d_in[7];
    const float* W2     = (const float*)d_in[8];
    const float* b2     = (const float*)d_in[9];
    const float* lin1_w = (const float*)d_in[10];
    const float* lin1_b = (const float*)d_in[11];
    const float* lin2_w = (const float*)d_in[12];
    const float* lin2_b = (const float*)d_in[13];

    const int N = in_sizes[0] / DD;
    const int E = in_sizes[1] / 2;
    const int* srcI = ei;
    const int* dstI = ei + E;

    // workspace layout
    float* A      = (float*)d_ws;                      // h buffer       (N*DD f32)
    float* G      = A + (size_t)N * DD;                // agg/z buffer   (N*DD f32)
    int*   rowptr = (int*)(G + (size_t)N * DD);        // N+1 ints
    int*   cursor = rowptr + (N + 1);                  // N ints (aliases cnt)
    int*   csr    = cursor + N;                        // E ints
    int*   cnt    = cursor;                            // histogram aliases cursor

    const size_t ldsBytes = (size_t)(DD * DD + DD * PAD) * sizeof(float);
    (void)hipFuncSetAttribute((const void*)gemm_fused_k<true, true>,
                              hipFuncAttributeMaxDynamicSharedMemorySize, (int)ldsBytes);
    (void)hipFuncSetAttribute((const void*)gemm_fused_k<false, false>,
                              hipFuncAttributeMaxDynamicSharedMemorySize, (int)ldsBytes);

    const int gemmGrid = (N + 127) / 128;
    const int edgeGrid = (E + 255) / 256;

    // ---- build CSR (once per call) ----
    hipMemsetAsync(cnt, 0, (size_t)N * sizeof(int), stream);
    hist_k<<<edgeGrid, 256, 0, stream>>>(dstI, cnt, E);
    scan_k<<<1, 1024, 0, stream>>>(cnt, rowptr, cursor, N, (N + 1023) / 1024);
    fill_k<<<edgeGrid, 256, 0, stream>>>(srcI, dstI, cursor, csr, E);

    // ---- layers ----
    const float* hcur = x;
    for (int l = 0; l < 5; ++l) {
        gather_k<<<(N + 7) / 8, 256, 0, stream>>>(hcur, rowptr, csr, G, N);
        // z = relu(BN((h+agg) @ W1 + b1)) -> G (in-place safe: tile staged)
        gemm_fused_k<true, true><<<gemmGrid, 256, ldsBytes, stream>>>(
            hcur, G, W1 + (size_t)l * DD * DD, b1 + (size_t)l * DD,
            gamma + (size_t)l * DD, beta + (size_t)l * DD,
            mean + (size_t)l * DD, var + (size_t)l * DD, G, N);
        // h = relu(z @ W2 + b2) -> A
        gemm_fused_k<false, false><<<gemmGrid, 256, ldsBytes, stream>>>(
            G, nullptr, W2 + (size_t)l * DD * DD, b2 + (size_t)l * DD,
            nullptr, nullptr, nullptr, nullptr, A, N);
        hcur = A;
    }
    // lin1
    gemm_fused_k<false, false><<<gemmGrid, 256, ldsBytes, stream>>>(
        A, nullptr, lin1_w, lin1_b, nullptr, nullptr, nullptr, nullptr, G, N);
    // lin2 + log_softmax
    lin2_lsm_k<<<(N + 3) / 4, 256, 0, stream>>>(G, lin2_w, lin2_b, (float*)d_out, N);
}

// Round 3
// 786.924 us; speedup vs baseline: 18.4021x; 2.4997x over previous
//
#include <hip/hip_runtime.h>
#include <hip/hip_bf16.h>

#define DD 128

typedef __attribute__((ext_vector_type(8))) short short8;
typedef __attribute__((ext_vector_type(4))) float f32x4;

__device__ __forceinline__ float bf2f(short s) {
    union { unsigned u; float f; } c; c.u = ((unsigned)(unsigned short)s) << 16; return c.f;
}
__device__ __forceinline__ short f2bf(float f) {   // round-to-nearest-even
    union { float f; unsigned u; } c; c.f = f;
    unsigned u = c.u + 0x7fffu + ((c.u >> 16) & 1u);
    return (short)(u >> 16);
}

// ---------------------------------------------------------------------------
// x (fp32) -> bf16
// ---------------------------------------------------------------------------
__global__ __launch_bounds__(256) void f2b_k(
    const float* __restrict__ x, ushort* __restrict__ o, int n8)
{
    int i = blockIdx.x * 256 + threadIdx.x;
    if (i < n8) {
        float4 v0 = ((const float4*)x)[(size_t)i * 2];
        float4 v1 = ((const float4*)x)[(size_t)i * 2 + 1];
        short8 r;
        r[0] = f2bf(v0.x); r[1] = f2bf(v0.y); r[2] = f2bf(v0.z); r[3] = f2bf(v0.w);
        r[4] = f2bf(v1.x); r[5] = f2bf(v1.y); r[6] = f2bf(v1.z); r[7] = f2bf(v1.w);
        ((short8*)o)[i] = r;
    }
}

// ---------------------------------------------------------------------------
// Weights: W[k][n] fp32 -> Wt[n][k] bf16, XOR-swizzled (ushort idx ^= (n&7)<<3)
// mats 0-4: W1 layers, 5-9: W2 layers, 10: lin1_w. 11*16384 elements.
// ---------------------------------------------------------------------------
__global__ __launch_bounds__(256) void wconv_k(
    const float* __restrict__ W1, const float* __restrict__ W2,
    const float* __restrict__ L1, ushort* __restrict__ Wt)
{
    int idx = blockIdx.x * 256 + threadIdx.x;
    int mat = idx >> 14;
    if (mat >= 11) return;
    int e = idx & 16383;
    int k = e >> 7, n = e & 127;
    const float* src = (mat < 5) ? (W1 + (size_t)mat * 16384)
                     : (mat < 10) ? (W2 + (size_t)(mat - 5) * 16384) : L1;
    float v = src[e];                       // e = k*128+n (coalesced)
    int di = (n * 128 + k) ^ ((n & 7) << 3);
    Wt[(size_t)mat * 16384 + di] = (ushort)f2bf(v);
}

// ---------------------------------------------------------------------------
// CSR build: histogram -> hierarchical exclusive scan -> fill
// ---------------------------------------------------------------------------
__global__ __launch_bounds__(256) void hist_k(
    const int* __restrict__ dst, int* __restrict__ cnt, int nEdges)
{
    int e = blockIdx.x * 256 + threadIdx.x;
    if (e < nEdges) atomicAdd(&cnt[dst[e]], 1);
}

__global__ __launch_bounds__(256) void reduce_k(
    const int* __restrict__ cnt, int* __restrict__ bsum, int n)
{
    __shared__ int s[256];
    int t = threadIdx.x;
    int base = blockIdx.x * 1024 + t * 4;
    int v = 0;
    if (base + 3 < n) { int4 c = *(const int4*)(cnt + base); v = c.x + c.y + c.z + c.w; }
    else { for (int i = 0; i < 4; ++i) if (base + i < n) v += cnt[base + i]; }
    s[t] = v; __syncthreads();
    for (int off = 128; off >= 1; off >>= 1) {
        if (t < off) s[t] += s[t + off];
        __syncthreads();
    }
    if (t == 0) bsum[blockIdx.x] = s[0];
}

__global__ __launch_bounds__(128) void scantop_k(
    int* __restrict__ bsum, int* __restrict__ totalOut, int nb)
{
    __shared__ int s[128];
    int t = threadIdx.x;
    int v = (t < nb) ? bsum[t] : 0;
    s[t] = v; __syncthreads();
    for (int off = 1; off < 128; off <<= 1) {
        int u = (t >= off) ? s[t - off] : 0;
        __syncthreads();
        s[t] += u;
        __syncthreads();
    }
    if (t < nb) bsum[t] = s[t] - v;       // exclusive
    if (t == 127) totalOut[0] = s[127];   // rowptr[N]
}

__global__ __launch_bounds__(256) void scanapply_k(
    const int* __restrict__ cnt, const int* __restrict__ bsum,
    int* __restrict__ rowptr, int* __restrict__ cursor, int n)
{
    __shared__ int s[256];
    int t = threadIdx.x;
    int base = blockIdx.x * 1024 + t * 4;
    int c[4]; int v = 0;
    for (int i = 0; i < 4; ++i) { c[i] = (base + i < n) ? cnt[base + i] : 0; v += c[i]; }
    s[t] = v; __syncthreads();
    int mine = v;
    for (int off = 1; off < 256; off <<= 1) {
        int u = (t >= off) ? s[t - off] : 0;
        __syncthreads();
        s[t] += u;
        __syncthreads();
    }
    int run = bsum[blockIdx.x] + s[t] - mine;
    for (int i = 0; i < 4; ++i) {
        if (base + i < n) { rowptr[base + i] = run; cursor[base + i] = run; run += c[i]; }
    }
}

__global__ __launch_bounds__(256) void fill_k(
    const int* __restrict__ src, const int* __restrict__ dst,
    int* __restrict__ cursor, int* __restrict__ csr, int nEdges)
{
    int e = blockIdx.x * 256 + threadIdx.x;
    if (e < nEdges) {
        int d = dst[e];
        int pos = atomicAdd(&cursor[d], 1);
        csr[pos] = src[e];
    }
}

// ---------------------------------------------------------------------------
// gather (bf16): out[i] = h[i] + sum_{k} h[csr[k]]   (fp32 accumulate)
//   16 lanes per node (16B each), 16 nodes per 256-thread block.
// ---------------------------------------------------------------------------
__global__ __launch_bounds__(256) void gather_bf_k(
    const ushort* __restrict__ h, const int* __restrict__ rowptr,
    const int* __restrict__ csr, ushort* __restrict__ out, int n)
{
    int node = blockIdx.x * 16 + (threadIdx.x >> 4);
    int j = threadIdx.x & 15;
    if (node >= n) return;
    int beg = rowptr[node], end = rowptr[node + 1];
    const short8* hp = (const short8*)h;

    float a[8];
    short8 v = hp[(size_t)node * 16 + j];
#pragma unroll
    for (int i = 0; i < 8; ++i) a[i] = bf2f(v[i]);

    int k = beg;
    for (; k + 1 < end; k += 2) {
        int s0 = csr[k], s1 = csr[k + 1];
        short8 v0 = hp[(size_t)s0 * 16 + j];
        short8 v1 = hp[(size_t)s1 * 16 + j];
#pragma unroll
        for (int i = 0; i < 8; ++i) a[i] += bf2f(v0[i]) + bf2f(v1[i]);
    }
    if (k < end) {
        int s0 = csr[k];
        short8 v0 = hp[(size_t)s0 * 16 + j];
#pragma unroll
        for (int i = 0; i < 8; ++i) a[i] += bf2f(v0[i]);
    }
    short8 r;
#pragma unroll
    for (int i = 0; i < 8; ++i) r[i] = f2bf(a[i]);
    ((short8*)out)[(size_t)node * 16 + j] = r;
}

// ---------------------------------------------------------------------------
// MFMA GEMM: O = relu(epi(A @ W + bias)), A bf16 [nrows][128], Wt swizzled bf16
//   block = 256 thr (4 waves), 128 rows/block; wave w: rows w*32..w*32+31.
//   mfma_f32_16x16x32_bf16: A-frag row=l&15,k=(l>>4)*8+b; B-frag col=l&15 same k;
//   C/D: col=l&15, row=(l>>4)*4+reg  [m89/m91 verified].
//   LDS XOR swizzle: byte ^= (row&7)<<4  (both write & read).
//   In-place safe (tile fully staged before writes).
// ---------------------------------------------------------------------------
template <bool BN>
__global__ __launch_bounds__(256) void gemm_mfma_k(
    const ushort* __restrict__ A, const ushort* __restrict__ Wt,
    const float* __restrict__ bias,
    const float* __restrict__ gamma, const float* __restrict__ beta,
    const float* __restrict__ mean, const float* __restrict__ var,
    ushort* __restrict__ O, int nrows)
{
    __shared__ ushort sA[16384];
    __shared__ ushort sW[16384];
    const int tid  = threadIdx.x;
    const int row0 = blockIdx.x * 128;

    // stage W (pre-swizzled in global -> linear copy)
    {
        const short8* srcv = (const short8*)Wt;
        short8* dstv = (short8*)sW;
#pragma unroll
        for (int i = 0; i < 8; ++i) dstv[i * 256 + tid] = srcv[i * 256 + tid];
    }
    // stage A with swizzle
    {
#pragma unroll
        for (int i = 0; i < 8; ++i) {
            int f  = i * 256 + tid;     // 16B chunk id (2048 per tile)
            int r  = f >> 4;            // local row
            int c8 = f & 15;
            int gr = row0 + r;
            short8 v = {0, 0, 0, 0, 0, 0, 0, 0};
            if (gr < nrows) v = *(const short8*)(A + (size_t)gr * DD + c8 * 8);
            int db = (r * 256 + c8 * 16) ^ ((r & 7) << 4);
            *(short8*)((char*)sA + db) = v;
        }
    }
    __syncthreads();

    const int lane = tid & 63;
    const int wv   = tid >> 6;
    const int m0   = wv * 32;
    const int lr   = lane & 15;
    const int lg   = lane >> 4;

    // epilogue constants per col-frag: n = cf*16 + lr
    float mul8[8], add8[8];
#pragma unroll
    for (int cf = 0; cf < 8; ++cf) {
        int n = cf * 16 + lr;
        if (BN) {
            float s = gamma[n] * rsqrtf(var[n] + 1e-5f);
            mul8[cf] = s;
            add8[cf] = (bias[n] - mean[n]) * s + beta[n];
        } else {
            mul8[cf] = 1.f;
            add8[cf] = bias[n];
        }
    }

    f32x4 acc[2][8];
#pragma unroll
    for (int rf = 0; rf < 2; ++rf)
#pragma unroll
        for (int cf = 0; cf < 8; ++cf) acc[rf][cf] = (f32x4){0.f, 0.f, 0.f, 0.f};

#pragma unroll
    for (int kk = 0; kk < 4; ++kk) {
        const int kb = kk * 64 + lg * 16;  // byte offset of this lane-group's k-slice
        int ra0 = m0 + lr;
        int ra1 = m0 + 16 + lr;
        short8 a0 = *(short8*)((char*)sA + ((ra0 * 256 + kb) ^ ((ra0 & 7) << 4)));
        short8 a1 = *(short8*)((char*)sA + ((ra1 * 256 + kb) ^ ((ra1 & 7) << 4)));
        short8 b[8];
#pragma unroll
        for (int cf = 0; cf < 8; ++cf) {
            int rn = cf * 16 + lr;
            b[cf] = *(short8*)((char*)sW + ((rn * 256 + kb) ^ ((rn & 7) << 4)));
        }
#pragma unroll
        for (int cf = 0; cf < 8; ++cf) {
            acc[0][cf] = __builtin_amdgcn_mfma_f32_16x16x32_bf16(a0, b[cf], acc[0][cf], 0, 0, 0);
            acc[1][cf] = __builtin_amdgcn_mfma_f32_16x16x32_bf16(a1, b[cf], acc[1][cf], 0, 0, 0);
        }
    }

    // epilogue + bf16 store
#pragma unroll
    for (int rf = 0; rf < 2; ++rf) {
#pragma unroll
        for (int cf = 0; cf < 8; ++cf) {
            int n = cf * 16 + lr;
#pragma unroll
            for (int i = 0; i < 4; ++i) {
                int m = row0 + m0 + rf * 16 + lg * 4 + i;
                if (m < nrows) {
                    float vv = fmaxf(fmaf(acc[rf][cf][i], mul8[cf], add8[cf]), 0.f);
                    O[(size_t)m * DD + n] = (ushort)f2bf(vv);
                }
            }
        }
    }
}

// ---------------------------------------------------------------------------
// lin2 (128 -> 10) + log_softmax, bf16 input. One wave per row.
// ---------------------------------------------------------------------------
__global__ __launch_bounds__(256) void lin2_lsm_k(
    const ushort* __restrict__ in, const float* __restrict__ w,
    const float* __restrict__ b, float* __restrict__ out, int n)
{
    int tid  = threadIdx.x;
    int lane = tid & 63;
    int row  = blockIdx.x * 4 + (tid >> 6);
    if (row >= n) return;

    const ushort* hr = in + (size_t)row * DD;
    float x0 = bf2f((short)hr[lane]);
    float x1 = bf2f((short)hr[lane + 64]);

    float p[10];
#pragma unroll
    for (int c = 0; c < 10; ++c)
        p[c] = fmaf(x0, w[lane * 10 + c], x1 * w[(lane + 64) * 10 + c]);

#pragma unroll
    for (int off = 32; off >= 1; off >>= 1) {
#pragma unroll
        for (int c = 0; c < 10; ++c) p[c] += __shfl_xor(p[c], off, 64);
    }
#pragma unroll
    for (int c = 0; c < 10; ++c) p[c] += b[c];

    float m = p[0];
#pragma unroll
    for (int c = 1; c < 10; ++c) m = fmaxf(m, p[c]);
    float s = 0.f;
#pragma unroll
    for (int c = 0; c < 10; ++c) s += expf(p[c] - m);
    float lse = m + logf(s);

    if (lane < 10) out[(size_t)row * 10 + lane] = p[lane] - lse;
}

// ---------------------------------------------------------------------------

extern "C" void kernel_launch(void* const* d_in, const int* in_sizes, int n_in,
                              void* d_out, int out_size, void* d_ws, size_t ws_size,
                              hipStream_t stream)
{
    const float* x      = (const float*)d_in[0];
    const int*   ei     = (const int*)d_in[1];
    const float* W1     = (const float*)d_in[2];
    const float* b1     = (const float*)d_in[3];
    const float* gamma  = (const float*)d_in[4];
    const float* beta   = (const float*)d_in[5];
    const float* mean   = (const float*)d_in[6];
    const float* var    = (const float*)d_in[7];
    const float* W2     = (const float*)d_in[8];
    const float* b2     = (const float*)d_in[9];
    const float* lin1_w = (const float*)d_in[10];
    const float* lin1_b = (const float*)d_in[11];
    const float* lin2_w = (const float*)d_in[12];
    const float* lin2_b = (const float*)d_in[13];

    const int N = in_sizes[0] / DD;
    const int E = in_sizes[1] / 2;
    const int* srcI = ei;
    const int* dstI = ei + E;

    // workspace layout (all 16B-aligned)
    ushort* hb     = (ushort*)d_ws;                 // N*128 bf16
    ushort* gb     = hb + (size_t)N * DD;           // N*128 bf16
    ushort* Wt     = gb + (size_t)N * DD;           // 11*16384 bf16 (swizzled)
    int*    rowptr = (int*)(Wt + 11 * 16384);       // N+4 ints
    int*    cnt    = rowptr + (N + 4);              // N ints (also cursor)
    int*    csr    = cnt + N;                       // E ints
    int*    bsum   = csr + E;                       // 128 ints

    const int nb       = (N + 1023) / 1024;
    const int gemmGrid = (N + 127) / 128;
    const int edgeGrid = (E + 255) / 256;

    // prep: bf16 conversions
    f2b_k<<<(N * DD / 8 + 255) / 256, 256, 0, stream>>>(x, hb, N * DD / 8);
    wconv_k<<<704, 256, 0, stream>>>(W1, W2, lin1_w, Wt);

    // CSR build
    hipMemsetAsync(cnt, 0, (size_t)N * sizeof(int), stream);
    hist_k<<<edgeGrid, 256, 0, stream>>>(dstI, cnt, E);
    reduce_k<<<nb, 256, 0, stream>>>(cnt, bsum, N);
    scantop_k<<<1, 128, 0, stream>>>(bsum, rowptr + N, nb);
    scanapply_k<<<nb, 256, 0, stream>>>(cnt, bsum, rowptr, cnt, N);
    fill_k<<<edgeGrid, 256, 0, stream>>>(srcI, dstI, cnt, csr, E);

    // layers
    for (int l = 0; l < 5; ++l) {
        gather_bf_k<<<(N + 15) / 16, 256, 0, stream>>>(hb, rowptr, csr, gb, N);
        gemm_mfma_k<true><<<gemmGrid, 256, 0, stream>>>(
            gb, Wt + (size_t)l * 16384, b1 + (size_t)l * DD,
            gamma + (size_t)l * DD, beta + (size_t)l * DD,
            mean + (size_t)l * DD, var + (size_t)l * DD, gb, N);
        gemm_mfma_k<false><<<gemmGrid, 256, 0, stream>>>(
            gb, Wt + (size_t)(5 + l) * 16384, b2 + (size_t)l * DD,
            nullptr, nullptr, nullptr, nullptr, hb, N);
    }
    // lin1
    gemm_mfma_k<false><<<gemmGrid, 256, 0, stream>>>(
        hb, Wt + (size_t)10 * 16384, lin1_b,
        nullptr, nullptr, nullptr, nullptr, gb, N);
    // lin2 + log_softmax
    lin2_lsm_k<<<(N + 3) / 4, 256, 0, stream>>>(gb, lin2_w, lin2_b, (float*)d_out, N);
}